// Round 3
// baseline (1357.582 us; speedup 1.0000x reference)
//
#include <hip/hip_runtime.h>
#include <math.h>

#define BB 8
#define CC 64
#define NN 32
#define CONV_TOTAL (BB*CC*NN*NN)   // 524288
#define KM_ELEMS (BB*9*CC*CC)      // 294912
#define NCANON 514                 // canonical frequencies per batch

// readlane with compile-time lane index (value broadcast, SGPR result)
#define RL(x, l) __uint_as_float(__builtin_amdgcn_readlane(__float_as_uint(x), (l)))

// Kernel A: km[b][j][o*64+i] = 0.7*tanh(pre[b,o,i,j]) + (o==i && j==4)
// Also zeroes the 8 logdet accumulators in d_out.
__global__ __launch_bounds__(256) void build_km(const float* __restrict__ pre,
                                                float* __restrict__ km,
                                                float* __restrict__ logdet_out) {
    int idx = blockIdx.x * 256 + threadIdx.x;
    if (blockIdx.x == 0 && threadIdx.x < BB) logdet_out[threadIdx.x] = 0.f;
    if (idx >= KM_ELEMS) return;
    int b   = idx / (9 * 4096);
    int rem = idx - b * (9 * 4096);
    int j   = rem >> 12;       // tap 0..8
    int e   = rem & 4095;      // o*64+i
    int o = e >> 6, i = e & 63;
    float v = 0.7f * tanhf(pre[(b * 4096 + e) * 9 + j]);
    if (o == i && j == 4) v += 1.0f;
    km[idx] = v;
}

// Kernel B: direct circular conv. One block per (b,o); 256 threads; each
// thread owns 4 consecutive pixels in a row.
__global__ __launch_bounds__(256) void conv_kernel(const float* __restrict__ x,
                                                   const float* __restrict__ km,
                                                   const float* __restrict__ bias,
                                                   float* __restrict__ out) {
    int b = blockIdx.x >> 6, o = blockIdx.x & 63;
    __shared__ float Kms[9][64];
    __shared__ float xs[1024];
    int t = threadIdx.x;
    for (int s = t; s < 576; s += 256) {
        int j = s >> 6, i = s & 63;
        Kms[j][i] = km[(b * 9 + j) * 4096 + (o << 6) + i];
    }
    float bb = bias[(b << 6) + o];
    float acc0 = bb, acc1 = bb, acc2 = bb, acc3 = bb;
    int u = t >> 3, v0 = (t & 7) << 2;
    const float* xb = x + (size_t)(b << 6) * 1024;
    for (int i = 0; i < 64; ++i) {
        float4 xv4 = *(const float4*)(xb + i * 1024 + (t << 2));
        __syncthreads();                       // previous iter done reading xs
        *(float4*)&xs[t << 2] = xv4;
        __syncthreads();                       // xs (and Kms on iter 0) visible
        #pragma unroll
        for (int dy = 0; dy < 3; ++dy) {
            int row = (u + 1 - dy) & 31;
            const float* xr = &xs[row << 5];
            float xv[6];
            #pragma unroll
            for (int q = 0; q < 6; ++q) xv[q] = xr[(v0 - 1 + q) & 31];
            #pragma unroll
            for (int dx = 0; dx < 3; ++dx) {
                float w = Kms[dy * 3 + dx][i];
                acc0 += w * xv[2 - dx];
                acc1 += w * xv[3 - dx];
                acc2 += w * xv[4 - dx];
                acc3 += w * xv[5 - dx];
            }
        }
    }
    float4 r = make_float4(acc0, acc1, acc2, acc3);
    *(float4*)(out + ((size_t)blockIdx.x << 10) + (u << 5) + v0) = r;
}

// Kernel C: one WAVE per canonical frequency. Matrix held entirely in
// registers, row-per-lane (re[64], im[64] = 128 VGPRs). Fully unrolled
// unpivoted LU: pivot row broadcast via v_readlane (compile-time lane),
// dead rows neutralized with m=0 (no exec divergence). No LDS, no barriers.
__global__ __launch_bounds__(64, 3) void logdet_kernel(const float* __restrict__ km,
                                                       float* __restrict__ logdet_out) {
    int gid = blockIdx.x;                 // one wave per block
    int b = gid / NCANON, ci = gid - b * NCANON;
    // canonical index -> (u,v)
    int u, v;
    if (ci < 17)        { u = 0;                  v = ci; }
    else if (ci < 497)  { int r = ci - 17; u = 1 + (r >> 5); v = r & 31; }
    else                { u = 16;                 v = ci - 497; }
    float wgt = ((u == 0 || u == 16) && (v == 0 || v == 16)) ? 1.0f : 2.0f;

    int lane = threadIdx.x;               // 64 threads = 1 wave

    float re[64], im[64];
    #pragma unroll
    for (int c = 0; c < 64; ++c) { re[c] = 0.f; im[c] = 0.f; }

    // Build row `lane`: A[lane][c] = sum_j km[b][j][lane*64+c] * w[j]
    const float* Kb = km + (size_t)b * 36864 + (lane << 6);
    #pragma unroll
    for (int j = 0; j < 9; ++j) {
        int dy = j / 3, dx = j % 3;
        float arg = -(float)(u * (dy - 1) + v * (dx - 1)) * (1.0f / 16.0f);
        float sn, cs;
        sincospif(arg, &sn, &cs);
        const float* p = Kb + (j << 12);
        #pragma unroll
        for (int t = 0; t < 16; ++t) {
            float4 kv = *(const float4*)(p + (t << 2));
            re[4*t+0] = fmaf(kv.x, cs, re[4*t+0]); im[4*t+0] = fmaf(kv.x, sn, im[4*t+0]);
            re[4*t+1] = fmaf(kv.y, cs, re[4*t+1]); im[4*t+1] = fmaf(kv.y, sn, im[4*t+1]);
            re[4*t+2] = fmaf(kv.z, cs, re[4*t+2]); im[4*t+2] = fmaf(kv.z, sn, im[4*t+2]);
            re[4*t+3] = fmaf(kv.w, cs, re[4*t+3]); im[4*t+3] = fmaf(kv.w, sn, im[4*t+3]);
        }
    }

    // Unpivoted LU, fully unrolled; log|det| accumulates wave-uniformly.
    float logsum = 0.f;
    #pragma unroll
    for (int k = 0; k < 64; ++k) {
        float px = RL(re[k], k), py = RL(im[k], k);       // pivot (uniform)
        float mag = fmaf(px, px, py * py);
        logsum += 0.5f * __logf(mag);
        if (k == 63) break;
        float inv = __builtin_amdgcn_rcpf(mag);
        // multiplier for this lane's row (garbage on rows <= k, zeroed below)
        float mr = (re[k] * px + im[k] * py) * inv;
        float mi = (im[k] * px - re[k] * py) * inv;
        bool act = lane > k;
        mr = act ? mr : 0.f;
        mi = act ? mi : 0.f;
        #pragma unroll
        for (int c = k + 1; c < 64; ++c) {
            float pcx = RL(re[c], k), pcy = RL(im[c], k); // pivot-row elem (uniform)
            re[c] = fmaf(-mr, pcx, fmaf(mi, pcy, re[c]));
            im[c] = fmaf(-mr, pcy, fmaf(-mi, pcx, im[c]));
        }
    }
    if (lane == 0) atomicAdd(&logdet_out[b], wgt * logsum);
}

extern "C" void kernel_launch(void* const* d_in, const int* in_sizes, int n_in,
                              void* d_out, int out_size, void* d_ws, size_t ws_size,
                              hipStream_t stream) {
    const float* conv_in    = (const float*)d_in[0];
    const float* pre_kernel = (const float*)d_in[1];
    const float* bias       = (const float*)d_in[2];
    float* out = (float*)d_out;
    float* km  = (float*)d_ws;                 // 294912 floats = 1.18 MB
    float* logdet_out = out + CONV_TOTAL;

    build_km<<<KM_ELEMS / 256, 256, 0, stream>>>(pre_kernel, km, logdet_out);
    conv_kernel<<<BB * CC, 256, 0, stream>>>(conv_in, km, bias, out);
    logdet_kernel<<<BB * NCANON, 64, 0, stream>>>(km, logdet_out);
}

// Round 4
// 217.651 us; speedup vs baseline: 6.2374x; 6.2374x over previous
//
#include <hip/hip_runtime.h>
#include <math.h>

#define BB 8
#define CC 64
#define NN 32
#define CONV_TOTAL (BB*CC*NN*NN)   // 524288
#define KM_ELEMS (BB*9*CC*CC)      // 294912
#define NCANON 514                 // canonical frequencies per batch

typedef float v2f __attribute__((ext_vector_type(2)));

// readlane with compile-time lane index (uniform broadcast)
#define RL(x, l) __uint_as_float(__builtin_amdgcn_readlane(__float_as_uint(x), (l)))

// Kernel A: km[b][j][o*64+i] = 0.7*tanh(pre[b,o,i,j]) + (o==i && j==4)
// Also zeroes the 8 logdet accumulators in d_out.
__global__ __launch_bounds__(256) void build_km(const float* __restrict__ pre,
                                                float* __restrict__ km,
                                                float* __restrict__ logdet_out) {
    int idx = blockIdx.x * 256 + threadIdx.x;
    if (blockIdx.x == 0 && threadIdx.x < BB) logdet_out[threadIdx.x] = 0.f;
    if (idx >= KM_ELEMS) return;
    int b   = idx / (9 * 4096);
    int rem = idx - b * (9 * 4096);
    int j   = rem >> 12;       // tap 0..8
    int e   = rem & 4095;      // o*64+i
    int o = e >> 6, i = e & 63;
    float v = 0.7f * tanhf(pre[(b * 4096 + e) * 9 + j]);
    if (o == i && j == 4) v += 1.0f;
    km[idx] = v;
}

// Kernel B: direct circular conv. One block per (b,o); 256 threads; each
// thread owns 4 consecutive pixels in a row.
__global__ __launch_bounds__(256) void conv_kernel(const float* __restrict__ x,
                                                   const float* __restrict__ km,
                                                   const float* __restrict__ bias,
                                                   float* __restrict__ out) {
    int b = blockIdx.x >> 6, o = blockIdx.x & 63;
    __shared__ float Kms[9][64];
    __shared__ float xs[1024];
    int t = threadIdx.x;
    for (int s = t; s < 576; s += 256) {
        int j = s >> 6, i = s & 63;
        Kms[j][i] = km[(b * 9 + j) * 4096 + (o << 6) + i];
    }
    float bb = bias[(b << 6) + o];
    float acc0 = bb, acc1 = bb, acc2 = bb, acc3 = bb;
    int u = t >> 3, v0 = (t & 7) << 2;
    const float* xb = x + (size_t)(b << 6) * 1024;
    for (int i = 0; i < 64; ++i) {
        float4 xv4 = *(const float4*)(xb + i * 1024 + (t << 2));
        __syncthreads();                       // previous iter done reading xs
        *(float4*)&xs[t << 2] = xv4;
        __syncthreads();                       // xs (and Kms on iter 0) visible
        #pragma unroll
        for (int dy = 0; dy < 3; ++dy) {
            int row = (u + 1 - dy) & 31;
            const float* xr = &xs[row << 5];
            float xv[6];
            #pragma unroll
            for (int q = 0; q < 6; ++q) xv[q] = xr[(v0 - 1 + q) & 31];
            #pragma unroll
            for (int dx = 0; dx < 3; ++dx) {
                float w = Kms[dy * 3 + dx][i];
                acc0 += w * xv[2 - dx];
                acc1 += w * xv[3 - dx];
                acc2 += w * xv[4 - dx];
                acc3 += w * xv[5 - dx];
            }
        }
    }
    float4 r = make_float4(acc0, acc1, acc2, acc3);
    *(float4*)(out + ((size_t)blockIdx.x << 10) + (u << 5) + v0) = r;
}

// ---- fully static unpivoted LU via template recursion --------------------
// Each lane owns row `lane` as v2f A[64] (128 VGPRs). All indices are
// template constants -> guaranteed register allocation (no scratch).
template<int K>
__device__ __forceinline__ void lu_steps(v2f (&A)[64], int lane, float &logsum) {
    float px = RL(A[K].x, K), py = RL(A[K].y, K);    // pivot (uniform)
    float mag = fmaf(px, px, py * py);
    logsum += 0.5f * __logf(mag);
    if constexpr (K < 63) {
        float inv = __builtin_amdgcn_rcpf(mag);
        float ax = A[K].x, ay = A[K].y;
        float mr = (ax * px + ay * py) * inv;        // this row's multiplier
        float mi = (ay * px - ax * py) * inv;
        bool act = lane > K;
        mr = act ? mr : 0.f;                         // dead rows: m = 0
        mi = act ? mi : 0.f;
        v2f m1 = (v2f){-mr, -mr};
        v2f m2 = (v2f){ mi, -mi};
        #pragma unroll
        for (int c = K + 1; c < 64; ++c) {
            float pcx = RL(A[c].x, K), pcy = RL(A[c].y, K);  // pivot-row elem
            v2f p1 = (v2f){pcx, pcy};
            v2f p2 = (v2f){pcy, pcx};
            A[c] = m1 * p1 + A[c];                   // v_pk_fma_f32 (contract)
            A[c] = m2 * p2 + A[c];
        }
        lu_steps<K + 1>(A, lane, logsum);
    }
}

// Kernel C: one wave per canonical frequency; matrix in registers.
__global__ __launch_bounds__(64, 3) void logdet_kernel(const float* __restrict__ km,
                                                       float* __restrict__ logdet_out) {
    int gid = blockIdx.x;
    int b = gid / NCANON, ci = gid - b * NCANON;
    int u, v;
    if (ci < 17)        { u = 0;                  v = ci; }
    else if (ci < 497)  { int r = ci - 17; u = 1 + (r >> 5); v = r & 31; }
    else                { u = 16;                 v = ci - 497; }
    float wgt = ((u == 0 || u == 16) && (v == 0 || v == 16)) ? 1.0f : 2.0f;

    int lane = threadIdx.x;

    v2f A[64];
    #pragma unroll
    for (int c = 0; c < 64; ++c) A[c] = (v2f){0.f, 0.f};

    // Build row `lane`: A[c] = sum_j km[b][j][lane*64+c] * w[j]
    // twiddle w[j] = exp(-2*pi*i*(u*(dy-1)+v*(dx-1))/32) via HW v_sin/v_cos
    // (single instructions, input in revolutions -- no libcall, no spill).
    const float* Kb = km + (size_t)b * 36864 + (lane << 6);
    #pragma unroll
    for (int j = 0; j < 9; ++j) {
        int dy = j / 3, dx = j % 3;
        float argrev = -(float)(u * (dy - 1) + v * (dx - 1)) * (1.0f / 32.0f);
        argrev = argrev - floorf(argrev);            // [0,1)
        float cs = __builtin_amdgcn_cosf(argrev);
        float sn = __builtin_amdgcn_sinf(argrev);
        v2f csn = (v2f){cs, sn};
        const float* p = Kb + (j << 12);
        #pragma unroll
        for (int ch = 0; ch < 4; ++ch) {
            float4 k0 = *(const float4*)(p + (ch << 4) + 0);
            float4 k1 = *(const float4*)(p + (ch << 4) + 4);
            float4 k2 = *(const float4*)(p + (ch << 4) + 8);
            float4 k3 = *(const float4*)(p + (ch << 4) + 12);
            A[(ch << 4) +  0] += csn * k0.x;  A[(ch << 4) +  1] += csn * k0.y;
            A[(ch << 4) +  2] += csn * k0.z;  A[(ch << 4) +  3] += csn * k0.w;
            A[(ch << 4) +  4] += csn * k1.x;  A[(ch << 4) +  5] += csn * k1.y;
            A[(ch << 4) +  6] += csn * k1.z;  A[(ch << 4) +  7] += csn * k1.w;
            A[(ch << 4) +  8] += csn * k2.x;  A[(ch << 4) +  9] += csn * k2.y;
            A[(ch << 4) + 10] += csn * k2.z;  A[(ch << 4) + 11] += csn * k2.w;
            A[(ch << 4) + 12] += csn * k3.x;  A[(ch << 4) + 13] += csn * k3.y;
            A[(ch << 4) + 14] += csn * k3.z;  A[(ch << 4) + 15] += csn * k3.w;
            __builtin_amdgcn_sched_barrier(0);       // cap loads in flight
        }
    }

    float logsum = 0.f;
    lu_steps<0>(A, lane, logsum);                    // fully static LU

    if (lane == 0) atomicAdd(&logdet_out[b], wgt * logsum);
}

extern "C" void kernel_launch(void* const* d_in, const int* in_sizes, int n_in,
                              void* d_out, int out_size, void* d_ws, size_t ws_size,
                              hipStream_t stream) {
    const float* conv_in    = (const float*)d_in[0];
    const float* pre_kernel = (const float*)d_in[1];
    const float* bias       = (const float*)d_in[2];
    float* out = (float*)d_out;
    float* km  = (float*)d_ws;                 // 294912 floats = 1.18 MB
    float* logdet_out = out + CONV_TOTAL;

    build_km<<<KM_ELEMS / 256, 256, 0, stream>>>(pre_kernel, km, logdet_out);
    conv_kernel<<<BB * CC, 256, 0, stream>>>(conv_in, km, bias, out);
    logdet_kernel<<<BB * NCANON, 64, 0, stream>>>(km, logdet_out);
}